// Round 10
// baseline (460.115 us; speedup 1.0000x reference)
//
#include <hip/hip_runtime.h>
#include <hip/hip_bf16.h>
#include <math.h>

#define N_NODES 50000
#define N_EDGES 800000
#define DIM 128
#define CLS 32
#define NGRAPH 64
#define LN_EPS 1e-5f
// padded CSR capacity: sum ceil(deg/8)*8 <= E + 7*N
#define CSR_CAP (N_EDGES + 8 * N_NODES)
#define NBLK 196                         // dst-buckets of 256 nodes
#define ABLK 128                         // phase-A blocks
#define EPB (N_EDGES / ABLK)             // 6250 edges per phase-A block
#define EB_STRIDE 7168                   // per-bucket ebuf capacity
#define LCAP 8192                        // per-bucket LDS csr capacity
#define PSPLIT 16                        // pool partial splits per graph
#define ROWS1 (N_NODES + 1)              // 50001 (incl zero pad row)
// col-blocked layout: Xc[g][n][c], g<8 groups of 16 cols, n<50001, c<16

typedef __attribute__((ext_vector_type(8))) short bf16x8;
typedef __attribute__((ext_vector_type(4))) float f32x4;

static __device__ __forceinline__ int lower_bound_i(const int* a, int n, int key) {
    int lo = 0, hi = n;
    while (lo < hi) { int mid = (lo + hi) >> 1; if (a[mid] < key) lo = mid + 1; else hi = mid; }
    return lo;
}

// ---- fused prep: col-blocked bf16 convert + weight transpose + zero scratch

__global__ __launch_bounds__(256) void prep_kernel(
    const float* __restrict__ x, const float* __restrict__ Wself,
    const float* __restrict__ Wmsg, __hip_bfloat16* __restrict__ XcIn,
    __hip_bfloat16* __restrict__ WT,
    int* __restrict__ ecur, float* __restrict__ gsum,
    __hip_bfloat16* __restrict__ padB, __hip_bfloat16* __restrict__ padC,
    __hip_bfloat16* __restrict__ padD) {
    int i = blockIdx.x * 256 + threadIdx.x;
    // col-blocked convert: i indexes col-pairs, 8*50001*8 total
    if (i < 8 * ROWS1 * 8) {
        int g = i / (ROWS1 * 8);
        int rem = i - g * (ROWS1 * 8);
        int n = rem >> 3;
        int cp = rem & 7;
        float2 v = make_float2(0.f, 0.f);
        if (n < N_NODES) {
            v.x = x[(size_t)n * DIM + g * 16 + cp * 2];
            v.y = x[(size_t)n * DIM + g * 16 + cp * 2 + 1];
        }
        ((__hip_bfloat162*)XcIn)[(size_t)(g * ROWS1 + n) * 8 + cp] = __float22bfloat162_rn(v);
    }
    if (i < 3 * 128 * 256) {
        int l = i / (128 * 256);
        int rem = i - l * (128 * 256);
        int n = rem >> 8;
        int k = rem & 255;
        float v = (k < 128) ? Wself[l * 16384 + k * 128 + n]
                            : Wmsg[l * 16384 + (k - 128) * 128 + n];
        WT[i] = __float2bfloat16(v);
    }
    if (i < NBLK) ecur[i] = i * EB_STRIDE;
    if (i < NGRAPH * DIM) gsum[i] = 0.f;
    if (i < 8 * 16) {  // zero pad row (n = N_NODES) of the other col-blocked bufs
        int g = i >> 4, c = i & 15;
        size_t off = (size_t)(g * ROWS1 + N_NODES) * 16 + c;
        padB[off] = __float2bfloat16(0.f);
        padC[off] = __float2bfloat16(0.f);
        padD[off] = __float2bfloat16(0.f);
    }
}

// ---- phase A: bucket edges by dst>>8, line-exclusive reservations ----------

__global__ __launch_bounds__(1024) void bucket_kernel(
    const int* __restrict__ esrc, const int* __restrict__ edst,
    int* __restrict__ ecur, int* __restrict__ ebuf) {
    __shared__ int bc[NBLK], bres[NBLK], bcnt[NBLK];
    const int t = threadIdx.x;
    const int e0 = blockIdx.x * EPB;
    if (t < NBLK) bc[t] = 0;
    __syncthreads();
    for (int i = t; i < EPB; i += 1024)
        atomicAdd(&bc[edst[e0 + i] >> 8], 1);
    __syncthreads();
    if (t < NBLK) {
        int c = bc[t];
        int r = (c + 15) & ~15;                 // whole 64B lines
        int res = atomicAdd(&ecur[t], r);       // one global atomic per (block,bucket)
        bres[t] = res;
        bcnt[t] = c;
        bc[t] = res;
    }
    __syncthreads();
    for (int i = t; i < EPB; i += 1024) {
        int d = edst[e0 + i];
        int s = esrc[e0 + i];
        int pos = atomicAdd(&bc[d >> 8], 1);
        ebuf[pos] = ((d & 255) << 16) | s;      // src < 50000 < 2^16
    }
    __syncthreads();
    if (t < NBLK) {
        int c = bcnt[t], r = (c + 15) & ~15, base = bres[t];
        for (int j = c; j < r; j++) ebuf[base + j] = -1;  // sentinels
    }
}

// ---- phase B1: per-bucket node histogram from ebuf -------------------------

__global__ __launch_bounds__(1024) void bhist_kernel(
    const int* __restrict__ ebuf, const int* __restrict__ ecur,
    int* __restrict__ counts, int* __restrict__ btot) {
    __shared__ int ncnt[256];
    __shared__ int red[256];
    const int b = blockIdx.x, t = threadIdx.x;
    const int used = ecur[b] - b * EB_STRIDE;
    const int* eb = ebuf + b * EB_STRIDE;
    if (t < 256) ncnt[t] = 0;
    __syncthreads();
    for (int i = t; i < used; i += 1024) {
        int p = eb[i];
        if (p != -1) atomicAdd(&ncnt[p >> 16], 1);
    }
    __syncthreads();
    if (t < 256) {
        int gi = b * 256 + t;
        if (gi < N_NODES) counts[gi] = ncnt[t];
        red[t] = (ncnt[t] + 7) & ~7;
    }
    __syncthreads();
    for (int o = 128; o > 0; o >>= 1) {
        if (t < o) red[t] += red[t + o];
        __syncthreads();
    }
    if (t == 0) btot[b] = red[0];
}

// ---- phase B2: exclusive scan of 196 padded bucket totals ------------------

__global__ __launch_bounds__(256) void btot_scan_kernel(const int* __restrict__ btot,
                                                        int* __restrict__ bbase,
                                                        int* __restrict__ off) {
    __shared__ int sd[256];
    int i = threadIdx.x;
    int v = (i < NBLK) ? btot[i] : 0;
    sd[i] = v;
    __syncthreads();
    for (int o = 1; o < 256; o <<= 1) {
        int tv = (i >= o) ? sd[i - o] : 0;
        __syncthreads();
        sd[i] += tv;
        __syncthreads();
    }
    if (i < NBLK) bbase[i] = sd[i] - v;  // exclusive
    if (i == 255) off[N_NODES] = sd[255];
}

// ---- phase B3: per-bucket CSR build in LDS; writes off[] + coalesced csr ---

__global__ __launch_bounds__(1024) void csr_build_kernel(
    const int* __restrict__ ebuf, const int* __restrict__ ecur,
    const int* __restrict__ counts, const int* __restrict__ bbase,
    int* __restrict__ off, int* __restrict__ csr) {
    __shared__ int cur[256];
    __shared__ int ssc[256];
    __shared__ int lcsr[LCAP];
    const int b = blockIdx.x, t = threadIdx.x;
    const int used = ecur[b] - b * EB_STRIDE;
    const int* eb = ebuf + b * EB_STRIDE;
    const int gbase = bbase[b];
    for (int i = t; i < LCAP; i += 1024) lcsr[i] = N_NODES;  // pads -> zero row
    int myc = 0, mypad = 0;
    const int gi = b * 256 + t;
    if (t < 256) {
        myc = (gi < N_NODES) ? counts[gi] : 0;
        mypad = (myc + 7) & ~7;
        ssc[t] = mypad;
    }
    __syncthreads();
    for (int o = 1; o < 256; o <<= 1) {
        int v = 0;
        if (t < 256 && t >= o) v = ssc[t - o];
        __syncthreads();
        if (t < 256) ssc[t] += v;
        __syncthreads();
    }
    if (t < 256) {
        int eoff = ssc[t] - mypad;
        cur[t] = eoff;
        if (gi < N_NODES) off[gi] = gbase + eoff;
    }
    __syncthreads();
    for (int i = t; i < used; i += 1024) {
        int p = eb[i];
        if (p != -1) {
            int pos = atomicAdd(&cur[p >> 16], 1);
            lcsr[pos] = p & 0xFFFF;
        }
    }
    __syncthreads();
    const int total = ssc[255];
    int4* dst4 = (int4*)(csr + gbase);
    const int4* src4 = (const int4*)lcsr;
    for (int i = t; i < (total >> 2); i += 1024) dst4[i] = src4[i];
}

// ---- Neighbor sum, col-blocked: Sc[g][n][:] = sum Xc[g][src][:] ------------
// Block = (4 nodes) x (col-group g = blockIdx & 7). Under the round-robin
// block->XCD mapping, each XCD's L2 keeps its 1.6 MB col slice resident.
// Wave = 1 node: 16 edges in flight (8 lanes/edge, 32 B/edge), subgroup-xor
// reduction, lanes 0..7 write a 32 B line-exclusive store.

__global__ __launch_bounds__(256) void agg_kernel(const __hip_bfloat16* __restrict__ Xc,
                                                  const int* __restrict__ off,
                                                  const int* __restrict__ csr,
                                                  __hip_bfloat16* __restrict__ Sc) {
    const int g = blockIdx.x & 7;
    const int wave = threadIdx.x >> 6;
    const int lane = threadIdx.x & 63;
    const int n = (blockIdx.x >> 3) * 4 + wave;
    if (n >= N_NODES) return;
    const __hip_bfloat16* Xg = Xc + (size_t)g * ROWS1 * 16;
    const int sub = lane >> 3;       // 0..7 edge subgroup
    const int cl = lane & 7;         // col pair within group
    int b = off[n], e = off[n + 1];  // padded: (e-b) % 8 == 0
    float ax = 0.f, ay = 0.f;
    int base = b;
    for (; base + 16 <= e; base += 16) {
        int idx16 = csr[base + (lane & 15)];
        int iA = __shfl(idx16, sub, 64);
        int iB = __shfl(idx16, sub + 8, 64);
        unsigned int vA = *(const unsigned int*)(Xg + (size_t)iA * 16 + cl * 2);
        unsigned int vB = *(const unsigned int*)(Xg + (size_t)iB * 16 + cl * 2);
        union { unsigned int u; float f; } w0, w1;
        w0.u = vA << 16; ax += w0.f;
        w1.u = vA & 0xffff0000u; ay += w1.f;
        w0.u = vB << 16; ax += w0.f;
        w1.u = vB & 0xffff0000u; ay += w1.f;
    }
    if (base < e) {  // 8-edge tail
        int idx8 = csr[base + (lane & 7)];
        int iA = __shfl(idx8, sub, 64);
        unsigned int vA = *(const unsigned int*)(Xg + (size_t)iA * 16 + cl * 2);
        union { unsigned int u; float f; } w0, w1;
        w0.u = vA << 16; ax += w0.f;
        w1.u = vA & 0xffff0000u; ay += w1.f;
    }
    // reduce across the 8 subgroups (lane bits 3,4,5)
#pragma unroll
    for (int m = 8; m < 64; m <<= 1) {
        ax += __shfl_xor(ax, m, 64);
        ay += __shfl_xor(ay, m, 64);
    }
    if (lane < 8) {
        __hip_bfloat162 p = __float22bfloat162_rn(make_float2(ax, ay));
        ((__hip_bfloat162*)(Sc + (size_t)(g * ROWS1 + n) * 16))[lane] = p;
    }
}

// ---- Fused layer via MFMA: H = [Xc|Sc] @ WT^T; +bias+deg*bmsg, ReLU, LN ----
// A-fragments read from col-blocked layout: 16 consecutive nodes x 32 B rows
// -> fully coalesced 16 B/lane loads. Output written col-blocked.

__global__ __launch_bounds__(256) void layer_mfma_kernel(
    const __hip_bfloat16* __restrict__ Xc, const __hip_bfloat16* __restrict__ Sc,
    const __hip_bfloat16* __restrict__ WT,  // [128 n][256 k] bf16 for this layer
    const float* __restrict__ bself, const float* __restrict__ bmsg,
    const int* __restrict__ deg,
    const float* __restrict__ lng, const float* __restrict__ lnb,
    __hip_bfloat16* __restrict__ XoutC, int do_ln) {
    __shared__ __hip_bfloat16 wlds[128 * 136];
    const int tid = threadIdx.x;
    const int w = tid >> 6, lane = tid & 63;
    const int l15 = lane & 15, q = lane >> 4;

    const int row = blockIdx.x * 64 + w * 16 + l15;
    const int rowc = min(row, N_NODES);  // pad row N_NODES is all zeros

    f32x4 acc[8];
#pragma unroll
    for (int ct = 0; ct < 8; ct++) acc[ct] = (f32x4){0.f, 0.f, 0.f, 0.f};

    const __hip_bfloat16* Abase[2] = {Xc, Sc};
    for (int c = 0; c < 2; c++) {
        __syncthreads();
        {
            int n = tid >> 1, h = tid & 1;
            const uint4* src = (const uint4*)(WT + n * 256 + c * 128 + h * 64);
            uint4* dst = (uint4*)(&wlds[n * 136 + h * 64]);
#pragma unroll
            for (int i = 0; i < 8; i++) dst[i] = src[i];
        }
        __syncthreads();
        const __hip_bfloat16* A = Abase[c];
#pragma unroll
        for (int ks = 0; ks < 4; ks++) {
            // cols ks*32 + q*8 .. +8  ->  group 2*ks + (q>>1), offset (q&1)*8
            int gg = 2 * ks + (q >> 1);
            bf16x8 afrag = *(const bf16x8*)(A + (size_t)(gg * ROWS1 + rowc) * 16 + (q & 1) * 8);
#pragma unroll
            for (int ct = 0; ct < 8; ct++) {
                bf16x8 bfrag = *(const bf16x8*)(&wlds[(ct * 16 + l15) * 136 + ks * 32 + q * 8]);
                acc[ct] = __builtin_amdgcn_mfma_f32_16x16x32_bf16(afrag, bfrag, acc[ct], 0, 0, 0);
            }
        }
    }

    // epilogue: lane holds rows (q*4+r), cols (ct*16+l15) -> group ct, col l15
    const int growbase = blockIdx.x * 64 + w * 16;
#pragma unroll
    for (int r = 0; r < 4; r++) {
        int grow = growbase + q * 4 + r;
        bool valid = grow < N_NODES;
        float dg = valid ? (float)deg[grow] : 0.f;
        float v[8];
        float s1 = 0.f;
#pragma unroll
        for (int ct = 0; ct < 8; ct++) {
            int col = ct * 16 + l15;
            float h = acc[ct][r] + bself[col] + dg * bmsg[col];
            h = fmaxf(h, 0.f);
            v[ct] = h;
            s1 += h;
        }
        if (do_ln) {
#pragma unroll
            for (int m = 1; m < 16; m <<= 1) s1 += __shfl_xor(s1, m, 64);
            float mu = s1 * (1.0f / 128.0f);
            float s2 = 0.f;
#pragma unroll
            for (int ct = 0; ct < 8; ct++) { float d = v[ct] - mu; s2 += d * d; }
#pragma unroll
            for (int m = 1; m < 16; m <<= 1) s2 += __shfl_xor(s2, m, 64);
            float rs = rsqrtf(s2 * (1.0f / 128.0f) + LN_EPS);
#pragma unroll
            for (int ct = 0; ct < 8; ct++) {
                int col = ct * 16 + l15;
                v[ct] = lng[col] * (v[ct] - mu) * rs + lnb[col];
            }
        }
        if (valid) {
#pragma unroll
            for (int ct = 0; ct < 8; ct++) {
                XoutC[(size_t)(ct * ROWS1 + grow) * 16 + l15] = __float2bfloat16(v[ct]);
            }
        }
    }
}

// ---- Global mean pool (partial sums, col-blocked input) + head -------------

__global__ __launch_bounds__(128) void pool_partial_kernel(const __hip_bfloat16* __restrict__ Xc,
                                                           const int* __restrict__ batch,
                                                           float* __restrict__ gsum) {
    int g = blockIdx.x;
    int s = blockIdx.y;
    int lo = lower_bound_i(batch, N_NODES, g);
    int hi = lower_bound_i(batch, N_NODES, g + 1);
    int len = hi - lo;
    int a = lo + (int)(((long long)len * s) / PSPLIT);
    int b = lo + (int)(((long long)len * (s + 1)) / PSPLIT);
    int c = threadIdx.x;
    const __hip_bfloat16* base = Xc + (size_t)(c >> 4) * ROWS1 * 16 + (c & 15);
    float acc = 0.f;
    for (int n = a; n < b; n++) acc += __bfloat162float(base[(size_t)n * 16]);
    if (b > a) atomicAdd(&gsum[g * DIM + c], acc);
}

__global__ __launch_bounds__(128) void head_kernel(
    const float* __restrict__ gsum, const int* __restrict__ batch,
    const float* __restrict__ W1, const float* __restrict__ b1,
    const float* __restrict__ W2, const float* __restrict__ b2,
    float* __restrict__ out) {
    __shared__ float p[128];
    __shared__ float hh[128];
    int g = blockIdx.x;
    int j = threadIdx.x;
    int lo = lower_bound_i(batch, N_NODES, g);
    int hi = lower_bound_i(batch, N_NODES, g + 1);
    float cnt = fmaxf((float)(hi - lo), 1.0f);
    p[j] = gsum[g * DIM + j] / cnt;
    __syncthreads();
    float s = b1[j];
    for (int k = 0; k < DIM; k++) s += p[k] * W1[k * DIM + j];
    hh[j] = s;
    __syncthreads();
    if (j < CLS) {
        float l = b2[j];
        for (int k = 0; k < DIM; k++) l += hh[k] * W2[k * CLS + j];
        float mx = l;
#pragma unroll
        for (int m = 16; m >= 1; m >>= 1) mx = fmaxf(mx, __shfl_xor(mx, m, 64));
        float ex = expf(l - mx);
        float se = ex;
#pragma unroll
        for (int m = 16; m >= 1; m >>= 1) se += __shfl_xor(se, m, 64);
        out[g * CLS + j] = l - mx - logf(se);
    }
}

// ---- launch ----------------------------------------------------------------

extern "C" void kernel_launch(void* const* d_in, const int* in_sizes, int n_in,
                              void* d_out, int out_size, void* d_ws, size_t ws_size,
                              hipStream_t stream) {
    (void)in_sizes; (void)n_in; (void)out_size; (void)ws_size;
    const float* x     = (const float*)d_in[0];
    const float* Wself = (const float*)d_in[1];
    const float* bself = (const float*)d_in[2];
    const float* Wmsg  = (const float*)d_in[3];
    const float* bmsg  = (const float*)d_in[4];
    const float* lng   = (const float*)d_in[5];
    const float* lnb   = (const float*)d_in[6];
    const float* W1    = (const float*)d_in[7];
    const float* b1    = (const float*)d_in[8];
    const float* W2    = (const float*)d_in[9];
    const float* b2    = (const float*)d_in[10];
    const int*   ei    = (const int*)d_in[11];
    const int*   batch = (const int*)d_in[12];
    const int* esrc = ei;
    const int* edst = ei + N_EDGES;

    char* w = (char*)d_ws;
    size_t o = 0;
    auto alloc = [&](size_t bytes) { void* p = w + o; o += (bytes + 255) & ~(size_t)255; return p; };
    __hip_bfloat16* XcIn = (__hip_bfloat16*)alloc((size_t)8 * ROWS1 * 16 * 2);
    __hip_bfloat16* Xc0  = (__hip_bfloat16*)alloc((size_t)8 * ROWS1 * 16 * 2);
    __hip_bfloat16* Xc1  = (__hip_bfloat16*)alloc((size_t)8 * ROWS1 * 16 * 2);
    __hip_bfloat16* Sc   = (__hip_bfloat16*)alloc((size_t)8 * ROWS1 * 16 * 2);
    __hip_bfloat16* WT   = (__hip_bfloat16*)alloc((size_t)3 * 128 * 256 * 2);
    int*   counts = (int*)alloc((size_t)N_NODES * 4);
    int*   offs   = (int*)alloc((size_t)(N_NODES + 1) * 4);
    int*   btot   = (int*)alloc((size_t)NBLK * 4);
    int*   bbase  = (int*)alloc((size_t)NBLK * 4);
    int*   ecur   = (int*)alloc((size_t)NBLK * 4);
    int*   ebuf   = (int*)alloc((size_t)NBLK * EB_STRIDE * 4);
    int*   csr    = (int*)alloc((size_t)CSR_CAP * 4);
    float* gsum   = (float*)alloc((size_t)NGRAPH * DIM * 4);

    // fused prep: col-blocked bf16 convert + WT transpose + zero scratch/pads
    prep_kernel<<<(8 * ROWS1 * 8 + 255) / 256, 256, 0, stream>>>(
        x, Wself, Wmsg, XcIn, WT, ecur, gsum, Xc0, Xc1, Sc);

    // CSR build: bucket -> per-bucket hist -> bucket scan -> LDS-local build
    bucket_kernel<<<ABLK, 1024, 0, stream>>>(esrc, edst, ecur, ebuf);
    bhist_kernel<<<NBLK, 1024, 0, stream>>>(ebuf, ecur, counts, btot);
    btot_scan_kernel<<<1, 256, 0, stream>>>(btot, bbase, offs);
    csr_build_kernel<<<NBLK, 1024, 0, stream>>>(ebuf, ecur, counts, bbase, offs, csr);

    const __hip_bfloat16* XcCur = XcIn;
    __hip_bfloat16* bbufs[3] = {Xc0, Xc1, Xc0};
    for (int i = 0; i < 3; i++) {
        agg_kernel<<<((N_NODES + 3) / 4) * 8, 256, 0, stream>>>(XcCur, offs, csr, Sc);
        layer_mfma_kernel<<<(N_NODES + 63) / 64, 256, 0, stream>>>(
            XcCur, Sc, WT + (size_t)i * 128 * 256,
            bself + i * DIM, bmsg + i * DIM, counts,
            (i < 2) ? lng + i * DIM : lng, (i < 2) ? lnb + i * DIM : lnb,
            bbufs[i], (i < 2) ? 1 : 0);
        XcCur = bbufs[i];
    }

    pool_partial_kernel<<<dim3(NGRAPH, PSPLIT), 128, 0, stream>>>(bbufs[2], batch, gsum);
    head_kernel<<<NGRAPH, 128, 0, stream>>>(gsum, batch, W1, b1, W2, b2, (float*)d_out);
}

// Round 11
// 354.430 us; speedup vs baseline: 1.2982x; 1.2982x over previous
//
#include <hip/hip_runtime.h>
#include <hip/hip_bf16.h>
#include <math.h>

#define N_NODES 50000
#define N_EDGES 800000
#define DIM 128
#define CLS 32
#define NGRAPH 64
#define LN_EPS 1e-5f
// padded CSR capacity: sum ceil(deg/8)*8 <= E + 7*N
#define CSR_CAP (N_EDGES + 8 * N_NODES)
#define NBLK 196                         // dst-buckets of 256 nodes
#define ABLK 128                         // phase-A blocks
#define EPB (N_EDGES / ABLK)             // 6250 edges per phase-A block
#define EB_STRIDE 7168                   // per-bucket ebuf capacity
#define LCAP 8192                        // per-bucket LDS csr capacity
#define PSPLIT 16                        // pool partial splits per graph
#define ROWS1 (N_NODES + 1)              // 50001 (incl zero pad row)
// col-blocked layout: Xc[g][n][c], g<4 groups of 32 cols (3.2 MB/group -> fits
// one XCD's 4MB L2; blockIdx&3 = g pins group g to XCDs {g, g+4})

typedef __attribute__((ext_vector_type(8))) short bf16x8;
typedef __attribute__((ext_vector_type(4))) float f32x4;

static __device__ __forceinline__ int lower_bound_i(const int* a, int n, int key) {
    int lo = 0, hi = n;
    while (lo < hi) { int mid = (lo + hi) >> 1; if (a[mid] < key) lo = mid + 1; else hi = mid; }
    return lo;
}

// ---- fused prep: col-blocked bf16 convert + weight transpose + zero scratch

__global__ __launch_bounds__(256) void prep_kernel(
    const float* __restrict__ x, const float* __restrict__ Wself,
    const float* __restrict__ Wmsg, __hip_bfloat16* __restrict__ XcIn,
    __hip_bfloat16* __restrict__ WT,
    int* __restrict__ ecur, float* __restrict__ gsum,
    __hip_bfloat16* __restrict__ padB, __hip_bfloat16* __restrict__ padC,
    __hip_bfloat16* __restrict__ padD) {
    int i = blockIdx.x * 256 + threadIdx.x;
    // col-blocked convert: i indexes col-pairs, 4*50001*16 total
    if (i < 4 * ROWS1 * 16) {
        int g = i / (ROWS1 * 16);
        int rem = i - g * (ROWS1 * 16);
        int n = rem >> 4;
        int cp = rem & 15;
        float2 v = make_float2(0.f, 0.f);
        if (n < N_NODES) {
            v.x = x[(size_t)n * DIM + g * 32 + cp * 2];
            v.y = x[(size_t)n * DIM + g * 32 + cp * 2 + 1];
        }
        ((__hip_bfloat162*)XcIn)[(size_t)(g * ROWS1 + n) * 16 + cp] = __float22bfloat162_rn(v);
    }
    if (i < 3 * 128 * 256) {
        int l = i / (128 * 256);
        int rem = i - l * (128 * 256);
        int n = rem >> 8;
        int k = rem & 255;
        float v = (k < 128) ? Wself[l * 16384 + k * 128 + n]
                            : Wmsg[l * 16384 + (k - 128) * 128 + n];
        WT[i] = __float2bfloat16(v);
    }
    if (i < NBLK) ecur[i] = i * EB_STRIDE;
    if (i < NGRAPH * DIM) gsum[i] = 0.f;
    if (i < 4 * 32) {  // zero pad row (n = N_NODES) of the other col-blocked bufs
        int g = i >> 5, c = i & 31;
        size_t off = (size_t)(g * ROWS1 + N_NODES) * 32 + c;
        padB[off] = __float2bfloat16(0.f);
        padC[off] = __float2bfloat16(0.f);
        padD[off] = __float2bfloat16(0.f);
    }
}

// ---- phase A: bucket edges by dst>>8, line-exclusive reservations ----------

__global__ __launch_bounds__(1024) void bucket_kernel(
    const int* __restrict__ esrc, const int* __restrict__ edst,
    int* __restrict__ ecur, int* __restrict__ ebuf) {
    __shared__ int bc[NBLK], bres[NBLK], bcnt[NBLK];
    const int t = threadIdx.x;
    const int e0 = blockIdx.x * EPB;
    if (t < NBLK) bc[t] = 0;
    __syncthreads();
    for (int i = t; i < EPB; i += 1024)
        atomicAdd(&bc[edst[e0 + i] >> 8], 1);
    __syncthreads();
    if (t < NBLK) {
        int c = bc[t];
        int r = (c + 15) & ~15;                 // whole 64B lines
        int res = atomicAdd(&ecur[t], r);       // one global atomic per (block,bucket)
        bres[t] = res;
        bcnt[t] = c;
        bc[t] = res;
    }
    __syncthreads();
    for (int i = t; i < EPB; i += 1024) {
        int d = edst[e0 + i];
        int s = esrc[e0 + i];
        int pos = atomicAdd(&bc[d >> 8], 1);
        ebuf[pos] = ((d & 255) << 16) | s;      // src < 50000 < 2^16
    }
    __syncthreads();
    if (t < NBLK) {
        int c = bcnt[t], r = (c + 15) & ~15, base = bres[t];
        for (int j = c; j < r; j++) ebuf[base + j] = -1;  // sentinels
    }
}

// ---- phase B1: per-bucket node histogram from ebuf -------------------------

__global__ __launch_bounds__(1024) void bhist_kernel(
    const int* __restrict__ ebuf, const int* __restrict__ ecur,
    int* __restrict__ counts, int* __restrict__ btot) {
    __shared__ int ncnt[256];
    __shared__ int red[256];
    const int b = blockIdx.x, t = threadIdx.x;
    const int used = ecur[b] - b * EB_STRIDE;
    const int* eb = ebuf + b * EB_STRIDE;
    if (t < 256) ncnt[t] = 0;
    __syncthreads();
    for (int i = t; i < used; i += 1024) {
        int p = eb[i];
        if (p != -1) atomicAdd(&ncnt[p >> 16], 1);
    }
    __syncthreads();
    if (t < 256) {
        int gi = b * 256 + t;
        if (gi < N_NODES) counts[gi] = ncnt[t];
        red[t] = (ncnt[t] + 7) & ~7;
    }
    __syncthreads();
    for (int o = 128; o > 0; o >>= 1) {
        if (t < o) red[t] += red[t + o];
        __syncthreads();
    }
    if (t == 0) btot[b] = red[0];
}

// ---- phase B2: exclusive scan of 196 padded bucket totals ------------------

__global__ __launch_bounds__(256) void btot_scan_kernel(const int* __restrict__ btot,
                                                        int* __restrict__ bbase,
                                                        int* __restrict__ off) {
    __shared__ int sd[256];
    int i = threadIdx.x;
    int v = (i < NBLK) ? btot[i] : 0;
    sd[i] = v;
    __syncthreads();
    for (int o = 1; o < 256; o <<= 1) {
        int tv = (i >= o) ? sd[i - o] : 0;
        __syncthreads();
        sd[i] += tv;
        __syncthreads();
    }
    if (i < NBLK) bbase[i] = sd[i] - v;  // exclusive
    if (i == 255) off[N_NODES] = sd[255];
}

// ---- phase B3: per-bucket CSR build in LDS; writes off[] + coalesced csr ---

__global__ __launch_bounds__(1024) void csr_build_kernel(
    const int* __restrict__ ebuf, const int* __restrict__ ecur,
    const int* __restrict__ counts, const int* __restrict__ bbase,
    int* __restrict__ off, int* __restrict__ csr) {
    __shared__ int cur[256];
    __shared__ int ssc[256];
    __shared__ int lcsr[LCAP];
    const int b = blockIdx.x, t = threadIdx.x;
    const int used = ecur[b] - b * EB_STRIDE;
    const int* eb = ebuf + b * EB_STRIDE;
    const int gbase = bbase[b];
    for (int i = t; i < LCAP; i += 1024) lcsr[i] = N_NODES;  // pads -> zero row
    int myc = 0, mypad = 0;
    const int gi = b * 256 + t;
    if (t < 256) {
        myc = (gi < N_NODES) ? counts[gi] : 0;
        mypad = (myc + 7) & ~7;
        ssc[t] = mypad;
    }
    __syncthreads();
    for (int o = 1; o < 256; o <<= 1) {
        int v = 0;
        if (t < 256 && t >= o) v = ssc[t - o];
        __syncthreads();
        if (t < 256) ssc[t] += v;
        __syncthreads();
    }
    if (t < 256) {
        int eoff = ssc[t] - mypad;
        cur[t] = eoff;
        if (gi < N_NODES) off[gi] = gbase + eoff;
    }
    __syncthreads();
    for (int i = t; i < used; i += 1024) {
        int p = eb[i];
        if (p != -1) {
            int pos = atomicAdd(&cur[p >> 16], 1);
            lcsr[pos] = p & 0xFFFF;
        }
    }
    __syncthreads();
    const int total = ssc[255];
    int4* dst4 = (int4*)(csr + gbase);
    const int4* src4 = (const int4*)lcsr;
    for (int i = t; i < (total >> 2); i += 1024) dst4[i] = src4[i];
}

// ---- Neighbor sum, 4-group col-blocked: Sc[g][n][:] = sum Xc[g][src][:] ----
// Block = 4 nodes x (group g = blockIdx & 3). XCD x serves only group x&3 ->
// each XCD's gather set = 3.2 MB, L2-resident. Wave = 1 node: 16 lanes/edge
// (64 B), 4 edge-subgroups, 4 gathers in flight per 16-edge chunk.

__global__ __launch_bounds__(256) void agg_kernel(const __hip_bfloat16* __restrict__ Xc,
                                                  const int* __restrict__ off,
                                                  const int* __restrict__ csr,
                                                  __hip_bfloat16* __restrict__ Sc) {
    const int g = blockIdx.x & 3;
    const int wave = threadIdx.x >> 6;
    const int lane = threadIdx.x & 63;
    const int n = (blockIdx.x >> 2) * 4 + wave;
    if (n >= N_NODES) return;
    const __hip_bfloat16* Xg = Xc + (size_t)g * ROWS1 * 32;
    const int sub = lane >> 4;       // edge subgroup 0..3
    const int cl = lane & 15;        // col-pair (4 B) within the 64 B row
    int b = off[n], e = off[n + 1];  // padded: (e-b) % 8 == 0
    float ax = 0.f, ay = 0.f;
    int base = b;
    for (; base + 16 <= e; base += 16) {
        int idx16 = csr[base + (lane & 15)];
        int i0 = __shfl(idx16, sub, 64);
        int i1 = __shfl(idx16, 4 + sub, 64);
        int i2 = __shfl(idx16, 8 + sub, 64);
        int i3 = __shfl(idx16, 12 + sub, 64);
        unsigned int v0 = *(const unsigned int*)(Xg + (size_t)i0 * 32 + cl * 2);
        unsigned int v1 = *(const unsigned int*)(Xg + (size_t)i1 * 32 + cl * 2);
        unsigned int v2 = *(const unsigned int*)(Xg + (size_t)i2 * 32 + cl * 2);
        unsigned int v3 = *(const unsigned int*)(Xg + (size_t)i3 * 32 + cl * 2);
        union { unsigned int u; float f; } w;
        w.u = v0 << 16; ax += w.f;  w.u = v0 & 0xffff0000u; ay += w.f;
        w.u = v1 << 16; ax += w.f;  w.u = v1 & 0xffff0000u; ay += w.f;
        w.u = v2 << 16; ax += w.f;  w.u = v2 & 0xffff0000u; ay += w.f;
        w.u = v3 << 16; ax += w.f;  w.u = v3 & 0xffff0000u; ay += w.f;
    }
    if (base < e) {  // 8-edge tail: subgroup handles edges sub, sub+4
        int idx8 = csr[base + (lane & 7)];
        int i0 = __shfl(idx8, sub, 64);
        int i1 = __shfl(idx8, 4 + sub, 64);
        unsigned int v0 = *(const unsigned int*)(Xg + (size_t)i0 * 32 + cl * 2);
        unsigned int v1 = *(const unsigned int*)(Xg + (size_t)i1 * 32 + cl * 2);
        union { unsigned int u; float f; } w;
        w.u = v0 << 16; ax += w.f;  w.u = v0 & 0xffff0000u; ay += w.f;
        w.u = v1 << 16; ax += w.f;  w.u = v1 & 0xffff0000u; ay += w.f;
    }
    // reduce across the 4 subgroups (lane bits 4,5)
    ax += __shfl_xor(ax, 16, 64); ay += __shfl_xor(ay, 16, 64);
    ax += __shfl_xor(ax, 32, 64); ay += __shfl_xor(ay, 32, 64);
    if (lane < 16) {
        __hip_bfloat162 p = __float22bfloat162_rn(make_float2(ax, ay));
        ((__hip_bfloat162*)(Sc + (size_t)(g * ROWS1 + n) * 32))[cl] = p;
    }
}

// ---- Fused layer via MFMA: H = [Xc|Sc] @ WT^T; +bias+deg*bmsg, ReLU, LN ----
// A-fragments: K-step ks covers cols ks*32..+31 = exactly group ks ->
// 16 consecutive nodes x 64 B rows, fully coalesced 16 B/lane loads.

__global__ __launch_bounds__(256) void layer_mfma_kernel(
    const __hip_bfloat16* __restrict__ Xc, const __hip_bfloat16* __restrict__ Sc,
    const __hip_bfloat16* __restrict__ WT,  // [128 n][256 k] bf16 for this layer
    const float* __restrict__ bself, const float* __restrict__ bmsg,
    const int* __restrict__ deg,
    const float* __restrict__ lng, const float* __restrict__ lnb,
    __hip_bfloat16* __restrict__ XoutC, int do_ln) {
    __shared__ __hip_bfloat16 wlds[128 * 136];
    const int tid = threadIdx.x;
    const int w = tid >> 6, lane = tid & 63;
    const int l15 = lane & 15, q = lane >> 4;

    const int row = blockIdx.x * 64 + w * 16 + l15;
    const int rowc = min(row, N_NODES);  // pad row N_NODES is all zeros

    f32x4 acc[8];
#pragma unroll
    for (int ct = 0; ct < 8; ct++) acc[ct] = (f32x4){0.f, 0.f, 0.f, 0.f};

    const __hip_bfloat16* Abase[2] = {Xc, Sc};
    for (int c = 0; c < 2; c++) {
        __syncthreads();
        {
            int n = tid >> 1, h = tid & 1;
            const uint4* src = (const uint4*)(WT + n * 256 + c * 128 + h * 64);
            uint4* dst = (uint4*)(&wlds[n * 136 + h * 64]);
#pragma unroll
            for (int i = 0; i < 8; i++) dst[i] = src[i];
        }
        __syncthreads();
        const __hip_bfloat16* A = Abase[c];
#pragma unroll
        for (int ks = 0; ks < 4; ks++) {
            // cols ks*32 + q*8 .. +8 -> group ks, offset q*8 within 32-col row
            bf16x8 afrag = *(const bf16x8*)(A + (size_t)(ks * ROWS1 + rowc) * 32 + q * 8);
#pragma unroll
            for (int ct = 0; ct < 8; ct++) {
                bf16x8 bfrag = *(const bf16x8*)(&wlds[(ct * 16 + l15) * 136 + ks * 32 + q * 8]);
                acc[ct] = __builtin_amdgcn_mfma_f32_16x16x32_bf16(afrag, bfrag, acc[ct], 0, 0, 0);
            }
        }
    }

    // epilogue: lane holds rows (q*4+r), cols (ct*16+l15)
    const int growbase = blockIdx.x * 64 + w * 16;
#pragma unroll
    for (int r = 0; r < 4; r++) {
        int grow = growbase + q * 4 + r;
        bool valid = grow < N_NODES;
        float dg = valid ? (float)deg[grow] : 0.f;
        float v[8];
        float s1 = 0.f;
#pragma unroll
        for (int ct = 0; ct < 8; ct++) {
            int col = ct * 16 + l15;
            float h = acc[ct][r] + bself[col] + dg * bmsg[col];
            h = fmaxf(h, 0.f);
            v[ct] = h;
            s1 += h;
        }
        if (do_ln) {
#pragma unroll
            for (int m = 1; m < 16; m <<= 1) s1 += __shfl_xor(s1, m, 64);
            float mu = s1 * (1.0f / 128.0f);
            float s2 = 0.f;
#pragma unroll
            for (int ct = 0; ct < 8; ct++) { float d = v[ct] - mu; s2 += d * d; }
#pragma unroll
            for (int m = 1; m < 16; m <<= 1) s2 += __shfl_xor(s2, m, 64);
            float rs = rsqrtf(s2 * (1.0f / 128.0f) + LN_EPS);
#pragma unroll
            for (int ct = 0; ct < 8; ct++) {
                int col = ct * 16 + l15;
                v[ct] = lng[col] * (v[ct] - mu) * rs + lnb[col];
            }
        }
        if (valid) {
#pragma unroll
            for (int ct = 0; ct < 8; ct++) {
                int col = ct * 16 + l15;
                XoutC[(size_t)((col >> 5) * ROWS1 + grow) * 32 + (col & 31)] =
                    __float2bfloat16(v[ct]);
            }
        }
    }
}

// ---- Global mean pool (partial sums, col-blocked input) + head -------------

__global__ __launch_bounds__(128) void pool_partial_kernel(const __hip_bfloat16* __restrict__ Xc,
                                                           const int* __restrict__ batch,
                                                           float* __restrict__ gsum) {
    int g = blockIdx.x;
    int s = blockIdx.y;
    int lo = lower_bound_i(batch, N_NODES, g);
    int hi = lower_bound_i(batch, N_NODES, g + 1);
    int len = hi - lo;
    int a = lo + (int)(((long long)len * s) / PSPLIT);
    int b = lo + (int)(((long long)len * (s + 1)) / PSPLIT);
    int c = threadIdx.x;
    const __hip_bfloat16* base = Xc + (size_t)(c >> 5) * ROWS1 * 32 + (c & 31);
    float acc = 0.f;
    for (int n = a; n < b; n++) acc += __bfloat162float(base[(size_t)n * 32]);
    if (b > a) atomicAdd(&gsum[g * DIM + c], acc);
}

__global__ __launch_bounds__(128) void head_kernel(
    const float* __restrict__ gsum, const int* __restrict__ batch,
    const float* __restrict__ W1, const float* __restrict__ b1,
    const float* __restrict__ W2, const float* __restrict__ b2,
    float* __restrict__ out) {
    __shared__ float p[128];
    __shared__ float hh[128];
    int g = blockIdx.x;
    int j = threadIdx.x;
    int lo = lower_bound_i(batch, N_NODES, g);
    int hi = lower_bound_i(batch, N_NODES, g + 1);
    float cnt = fmaxf((float)(hi - lo), 1.0f);
    p[j] = gsum[g * DIM + j] / cnt;
    __syncthreads();
    float s = b1[j];
    for (int k = 0; k < DIM; k++) s += p[k] * W1[k * DIM + j];
    hh[j] = s;
    __syncthreads();
    if (j < CLS) {
        float l = b2[j];
        for (int k = 0; k < DIM; k++) l += hh[k] * W2[k * CLS + j];
        float mx = l;
#pragma unroll
        for (int m = 16; m >= 1; m >>= 1) mx = fmaxf(mx, __shfl_xor(mx, m, 64));
        float ex = expf(l - mx);
        float se = ex;
#pragma unroll
        for (int m = 16; m >= 1; m >>= 1) se += __shfl_xor(se, m, 64);
        out[g * CLS + j] = l - mx - logf(se);
    }
}

// ---- launch ----------------------------------------------------------------

extern "C" void kernel_launch(void* const* d_in, const int* in_sizes, int n_in,
                              void* d_out, int out_size, void* d_ws, size_t ws_size,
                              hipStream_t stream) {
    (void)in_sizes; (void)n_in; (void)out_size; (void)ws_size;
    const float* x     = (const float*)d_in[0];
    const float* Wself = (const float*)d_in[1];
    const float* bself = (const float*)d_in[2];
    const float* Wmsg  = (const float*)d_in[3];
    const float* bmsg  = (const float*)d_in[4];
    const float* lng   = (const float*)d_in[5];
    const float* lnb   = (const float*)d_in[6];
    const float* W1    = (const float*)d_in[7];
    const float* b1    = (const float*)d_in[8];
    const float* W2    = (const float*)d_in[9];
    const float* b2    = (const float*)d_in[10];
    const int*   ei    = (const int*)d_in[11];
    const int*   batch = (const int*)d_in[12];
    const int* esrc = ei;
    const int* edst = ei + N_EDGES;

    char* w = (char*)d_ws;
    size_t o = 0;
    auto alloc = [&](size_t bytes) { void* p = w + o; o += (bytes + 255) & ~(size_t)255; return p; };
    __hip_bfloat16* XcIn = (__hip_bfloat16*)alloc((size_t)4 * ROWS1 * 32 * 2);
    __hip_bfloat16* Xc0  = (__hip_bfloat16*)alloc((size_t)4 * ROWS1 * 32 * 2);
    __hip_bfloat16* Xc1  = (__hip_bfloat16*)alloc((size_t)4 * ROWS1 * 32 * 2);
    __hip_bfloat16* Sc   = (__hip_bfloat16*)alloc((size_t)4 * ROWS1 * 32 * 2);
    __hip_bfloat16* WT   = (__hip_bfloat16*)alloc((size_t)3 * 128 * 256 * 2);
    int*   counts = (int*)alloc((size_t)N_NODES * 4);
    int*   offs   = (int*)alloc((size_t)(N_NODES + 1) * 4);
    int*   btot   = (int*)alloc((size_t)NBLK * 4);
    int*   bbase  = (int*)alloc((size_t)NBLK * 4);
    int*   ecur   = (int*)alloc((size_t)NBLK * 4);
    int*   ebuf   = (int*)alloc((size_t)NBLK * EB_STRIDE * 4);
    int*   csr    = (int*)alloc((size_t)CSR_CAP * 4);
    float* gsum   = (float*)alloc((size_t)NGRAPH * DIM * 4);

    // fused prep: col-blocked bf16 convert + WT transpose + zero scratch/pads
    prep_kernel<<<(4 * ROWS1 * 16 + 255) / 256, 256, 0, stream>>>(
        x, Wself, Wmsg, XcIn, WT, ecur, gsum, Xc0, Xc1, Sc);

    // CSR build: bucket -> per-bucket hist -> bucket scan -> LDS-local build
    bucket_kernel<<<ABLK, 1024, 0, stream>>>(esrc, edst, ecur, ebuf);
    bhist_kernel<<<NBLK, 1024, 0, stream>>>(ebuf, ecur, counts, btot);
    btot_scan_kernel<<<1, 256, 0, stream>>>(btot, bbase, offs);
    csr_build_kernel<<<NBLK, 1024, 0, stream>>>(ebuf, ecur, counts, bbase, offs, csr);

    const __hip_bfloat16* XcCur = XcIn;
    __hip_bfloat16* bbufs[3] = {Xc0, Xc1, Xc0};
    for (int i = 0; i < 3; i++) {
        agg_kernel<<<((N_NODES + 3) / 4) * 4, 256, 0, stream>>>(XcCur, offs, csr, Sc);
        layer_mfma_kernel<<<(N_NODES + 63) / 64, 256, 0, stream>>>(
            XcCur, Sc, WT + (size_t)i * 128 * 256,
            bself + i * DIM, bmsg + i * DIM, counts,
            (i < 2) ? lng + i * DIM : lng, (i < 2) ? lnb + i * DIM : lnb,
            bbufs[i], (i < 2) ? 1 : 0);
        XcCur = bbufs[i];
    }

    pool_partial_kernel<<<dim3(NGRAPH, PSPLIT), 128, 0, stream>>>(bbufs[2], batch, gsum);
    head_kernel<<<NGRAPH, 128, 0, stream>>>(gsum, batch, W1, b1, W2, b2, (float*)d_out);
}